// Round 1
// baseline (956.616 us; speedup 1.0000x reference)
//
#include <hip/hip_runtime.h>

// InteractionBlock: N=50000 nodes, M=32 nbrs, HID=128, FILT=128, NBR=64
//  k1 : per-node fused filter MLP (bf16 MFMA) + filter-weighted neighbor sum -> message (d_out)
//  k2a: u = silu(msg@uw1+ub1) -> bf16 u in d_ws
//  k2b: out = u@uw2+ub2 -> d_out
//
// MFMA layout conventions used (gfx950, 16x16 family, verified in guide m89/m91):
//   A frag (16x16x32): row = lane&15, k = (lane>>4)*8 + j   (8 contiguous k, short8)
//   B frag (16x16x32): col = lane&15, k = (lane>>4)*8 + j
//   A/B frag (16x16x16bf16_1k): same with 4 contiguous k (short4)
//   C/D:               col = lane&15, row = (lane>>4)*4 + reg
// Trick: transposed GEMM1 (C=h^T) yields per-lane 4 consecutive filt values ==
// exactly the A-fragment of 16x16x16 for GEMM2 -> zero-shuffle handoff.

#define NN 50000
#define MM 32
#define HID 128
#define NBR 64

typedef __attribute__((ext_vector_type(4))) float f32x4;
typedef __attribute__((ext_vector_type(8))) short s16x8;
typedef __attribute__((ext_vector_type(4))) short s16x4;

__device__ __forceinline__ short f2bf(float x) {
  // round-to-nearest-even f32 -> bf16 (inputs finite; no NaN handling needed)
  unsigned u = __builtin_bit_cast(unsigned, x);
  unsigned r = (u + 0x7FFFu + ((u >> 16) & 1u)) >> 16;
  return (short)r;
}

__device__ __forceinline__ float silu(float x) {
  return x / (1.0f + __expf(-x));
}

// ---------------------------------------------------------------- kernel 1
__global__ __launch_bounds__(256, 2) void k_filter_message(
    const float* __restrict__ node_repr, const float* __restrict__ nbr_fea,
    const int* __restrict__ nbr_idx, const float* __restrict__ fw1,
    const float* __restrict__ fb1, const float* __restrict__ fw2,
    const float* __restrict__ fb2, float* __restrict__ msg_out)
{
  // fw1T[f][k]: stride 72 shorts = 144B (16B-mult for b128 reads, odd*... breaks 16-way conflicts)
  // fw2T[h][k]: stride 136 shorts = 272B
  __shared__ __align__(16) short s_w1[128 * 72];
  __shared__ __align__(16) short s_w2[128 * 136];
  __shared__ float s_b1[128];
  __shared__ float s_b2[128];

  const int tid = threadIdx.x;
  for (int i = tid; i < 64 * 128; i += 256) {      // fw1 given [k<64][f<128]
    int k = i >> 7, f = i & 127;
    s_w1[f * 72 + k] = f2bf(fw1[i]);
  }
  for (int i = tid; i < 128 * 128; i += 256) {     // fw2 given [k<128][h<128]
    int k = i >> 7, h = i & 127;
    s_w2[h * 136 + k] = f2bf(fw2[i]);
  }
  if (tid < 128) { s_b1[tid] = fb1[tid]; s_b2[tid] = fb2[tid]; }
  __syncthreads();

  const int wave = tid >> 6, lane = tid & 63;
  const int c = lane & 15, g = lane >> 4;
  const int gw = blockIdx.x * 4 + wave;
  const int stride = gridDim.x * 4;

  for (int n = gw; n < NN; n += stride) {
    const float* nf = nbr_fea + (size_t)n * (MM * NBR);

    // neighbor indices this lane will need in the epilogue: m = 16*mt + 4*g + r
    int idxm[8];
    #pragma unroll
    for (int mt = 0; mt < 2; ++mt)
      #pragma unroll
      for (int r = 0; r < 4; ++r)
        idxm[mt * 4 + r] = nbr_idx[(size_t)n * MM + mt * 16 + g * 4 + r];

    // B1 frags: nbr^T, col m = 16mt+c, k = 32kt+8g..+7 (contiguous in nbr_fea row)
    s16x8 b1[2][2];
    #pragma unroll
    for (int mt = 0; mt < 2; ++mt)
      #pragma unroll
      for (int kt = 0; kt < 2; ++kt) {
        const float* src = nf + (mt * 16 + c) * NBR + kt * 32 + g * 8;
        float4 lo = *reinterpret_cast<const float4*>(src);
        float4 hi = *reinterpret_cast<const float4*>(src + 4);
        s16x8 v;
        v[0] = f2bf(lo.x); v[1] = f2bf(lo.y); v[2] = f2bf(lo.z); v[3] = f2bf(lo.w);
        v[4] = f2bf(hi.x); v[5] = f2bf(hi.y); v[6] = f2bf(hi.z); v[7] = f2bf(hi.w);
        b1[mt][kt] = v;
      }

    // GEMM1 (transposed): h^T[filt][m] = fw1T . nbr^T   (16x16x32)
    f32x4 acc1[8][2];
    #pragma unroll
    for (int t = 0; t < 8; ++t)
      #pragma unroll
      for (int mt = 0; mt < 2; ++mt)
        acc1[t][mt] = f32x4{0.f, 0.f, 0.f, 0.f};
    #pragma unroll
    for (int kt = 0; kt < 2; ++kt)
      #pragma unroll
      for (int t = 0; t < 8; ++t) {
        s16x8 a1 = *reinterpret_cast<const s16x8*>(&s_w1[(t * 16 + c) * 72 + kt * 32 + g * 8]);
        #pragma unroll
        for (int mt = 0; mt < 2; ++mt)
          acc1[t][mt] = __builtin_amdgcn_mfma_f32_16x16x32_bf16(a1, b1[mt][kt], acc1[t][mt], 0, 0, 0);
      }

    // bias + silu + pack: P[kt][mt] holds h~[m=16mt+c][filt=16kt+4g+{0..3}]
    //   == A-fragment of mfma_f32_16x16x16bf16_1k for GEMM2 (zero shuffle)
    s16x4 P[8][2];
    #pragma unroll
    for (int t = 0; t < 8; ++t)
      #pragma unroll
      for (int mt = 0; mt < 2; ++mt) {
        s16x4 p;
        #pragma unroll
        for (int r = 0; r < 4; ++r) {
          float x = acc1[t][mt][r] + s_b1[t * 16 + g * 4 + r];
          p[r] = f2bf(silu(x));
        }
        P[t][mt] = p;
      }

    // GEMM2: filters[m][hid] = h~ . fw2   (16x16x16)
    f32x4 acc2[8][2];
    #pragma unroll
    for (int ct = 0; ct < 8; ++ct)
      #pragma unroll
      for (int mt = 0; mt < 2; ++mt)
        acc2[ct][mt] = f32x4{0.f, 0.f, 0.f, 0.f};
    #pragma unroll
    for (int ct = 0; ct < 8; ++ct)
      #pragma unroll
      for (int kt = 0; kt < 8; ++kt) {
        s16x4 b2 = *reinterpret_cast<const s16x4*>(&s_w2[(ct * 16 + c) * 136 + kt * 16 + g * 4]);
        #pragma unroll
        for (int mt = 0; mt < 2; ++mt)
          acc2[ct][mt] = __builtin_amdgcn_mfma_f32_16x16x16bf16_1k(P[kt][mt], b2, acc2[ct][mt], 0, 0, 0);
      }

    // epilogue: message[hid] = sum_m (filters[m][hid]+fb2[hid]) * node_repr[idx[m]][hid]
    #pragma unroll
    for (int ct = 0; ct < 8; ++ct) {
      const float bias = s_b2[ct * 16 + c];
      float s = 0.f;
      #pragma unroll
      for (int mt = 0; mt < 2; ++mt)
        #pragma unroll
        for (int r = 0; r < 4; ++r) {
          float fv = acc2[ct][mt][r] + bias;   // m = 16mt + 4g + r, hid = 16ct + c
          float nr = node_repr[(size_t)idxm[mt * 4 + r] * HID + ct * 16 + c];
          s += fv * nr;
        }
      s += __shfl_xor(s, 16, 64);
      s += __shfl_xor(s, 32, 64);
      if (g == 0) msg_out[(size_t)n * HID + ct * 16 + c] = s;
    }
  }
}

// ---------------------------------------------------------------- kernel 2a
// u^T = silu(uw1^T . msg^T + ub1) -> bf16 u[row][128] in ws
__global__ __launch_bounds__(256, 2) void k_update1(
    const float* __restrict__ msg, const float* __restrict__ uw1,
    const float* __restrict__ ub1, short* __restrict__ u_out)
{
  __shared__ __align__(16) short s_w1[128 * 136];   // uw1T[f][k], stride 136
  __shared__ float s_b1[128];
  const int tid = threadIdx.x;
  for (int i = tid; i < 128 * 128; i += 256) {      // uw1 given [k][f]
    int k = i >> 7, f = i & 127;
    s_w1[f * 136 + k] = f2bf(uw1[i]);
  }
  if (tid < 128) s_b1[tid] = ub1[tid];
  __syncthreads();

  const int wave = tid >> 6, lane = tid & 63;
  const int c = lane & 15, g = lane >> 4;
  const long base = (long)(blockIdx.x * 4 + wave) * 32;
  if (base >= NN) return;

  // B frags from msg (f32 -> bf16): col m = base+16mt+c, k = 32kt+8g..+7
  s16x8 bfr[2][4];
  #pragma unroll
  for (int mt = 0; mt < 2; ++mt)
    #pragma unroll
    for (int kt = 0; kt < 4; ++kt) {
      long row = base + mt * 16 + c; if (row > NN - 1) row = NN - 1;
      const float* src = msg + row * HID + kt * 32 + g * 8;
      float4 lo = *reinterpret_cast<const float4*>(src);
      float4 hi = *reinterpret_cast<const float4*>(src + 4);
      s16x8 v;
      v[0] = f2bf(lo.x); v[1] = f2bf(lo.y); v[2] = f2bf(lo.z); v[3] = f2bf(lo.w);
      v[4] = f2bf(hi.x); v[5] = f2bf(hi.y); v[6] = f2bf(hi.z); v[7] = f2bf(hi.w);
      bfr[mt][kt] = v;
    }

  f32x4 acc[8][2];
  #pragma unroll
  for (int t = 0; t < 8; ++t)
    #pragma unroll
    for (int mt = 0; mt < 2; ++mt)
      acc[t][mt] = f32x4{0.f, 0.f, 0.f, 0.f};
  #pragma unroll
  for (int kt = 0; kt < 4; ++kt)
    #pragma unroll
    for (int t = 0; t < 8; ++t) {
      s16x8 a = *reinterpret_cast<const s16x8*>(&s_w1[(t * 16 + c) * 136 + kt * 32 + g * 8]);
      #pragma unroll
      for (int mt = 0; mt < 2; ++mt)
        acc[t][mt] = __builtin_amdgcn_mfma_f32_16x16x32_bf16(a, bfr[mt][kt], acc[t][mt], 0, 0, 0);
    }

  // silu + store u^T: lane holds u[m=base+16mt+c][filt=16t+4g+{0..3}] -> 8B store
  #pragma unroll
  for (int t = 0; t < 8; ++t)
    #pragma unroll
    for (int mt = 0; mt < 2; ++mt) {
      long row = base + mt * 16 + c;
      if (row < NN) {
        s16x4 p;
        #pragma unroll
        for (int r = 0; r < 4; ++r) {
          float x = acc[t][mt][r] + s_b1[t * 16 + g * 4 + r];
          p[r] = f2bf(silu(x));
        }
        *reinterpret_cast<s16x4*>(&u_out[row * HID + t * 16 + g * 4]) = p;
      }
    }
}

// ---------------------------------------------------------------- kernel 2b
// out[m][hid] = u . uw2 + ub2   (16x16x16, A from bf16 u in ws)
__global__ __launch_bounds__(256, 2) void k_update2(
    const short* __restrict__ u, const float* __restrict__ uw2,
    const float* __restrict__ ub2, float* __restrict__ out)
{
  __shared__ __align__(16) short s_w2[128 * 136];   // uw2T[h][k]
  __shared__ float s_b2[128];
  const int tid = threadIdx.x;
  for (int i = tid; i < 128 * 128; i += 256) {      // uw2 given [k][h]
    int k = i >> 7, h = i & 127;
    s_w2[h * 136 + k] = f2bf(uw2[i]);
  }
  if (tid < 128) s_b2[tid] = ub2[tid];
  __syncthreads();

  const int wave = tid >> 6, lane = tid & 63;
  const int c = lane & 15, g = lane >> 4;
  const long base = (long)(blockIdx.x * 4 + wave) * 32;
  if (base >= NN) return;

  // A frags: row m = base+16mt+c, k = 16kt+4g+{0..3} -> b64 from u
  s16x4 afr[2][8];
  #pragma unroll
  for (int mt = 0; mt < 2; ++mt)
    #pragma unroll
    for (int kt = 0; kt < 8; ++kt) {
      long row = base + mt * 16 + c; if (row > NN - 1) row = NN - 1;
      afr[mt][kt] = *reinterpret_cast<const s16x4*>(&u[row * HID + kt * 16 + g * 4]);
    }

  f32x4 acc[8][2];
  #pragma unroll
  for (int ct = 0; ct < 8; ++ct)
    #pragma unroll
    for (int mt = 0; mt < 2; ++mt)
      acc[ct][mt] = f32x4{0.f, 0.f, 0.f, 0.f};
  #pragma unroll
  for (int ct = 0; ct < 8; ++ct)
    #pragma unroll
    for (int kt = 0; kt < 8; ++kt) {
      s16x4 b2 = *reinterpret_cast<const s16x4*>(&s_w2[(ct * 16 + c) * 136 + kt * 16 + g * 4]);
      #pragma unroll
      for (int mt = 0; mt < 2; ++mt)
        acc[ct][mt] = __builtin_amdgcn_mfma_f32_16x16x16bf16_1k(afr[mt][kt], b2, acc[ct][mt], 0, 0, 0);
    }

  // store: out[m=base+16mt+4g+r][hid=16ct+c]
  #pragma unroll
  for (int ct = 0; ct < 8; ++ct) {
    const float bias = s_b2[ct * 16 + c];
    #pragma unroll
    for (int mt = 0; mt < 2; ++mt)
      #pragma unroll
      for (int r = 0; r < 4; ++r) {
        long row = base + mt * 16 + g * 4 + r;
        if (row < NN) out[row * HID + ct * 16 + c] = acc[ct][mt][r] + bias;
      }
  }
}

// ---------------------------------------------------------------- launch
extern "C" void kernel_launch(void* const* d_in, const int* in_sizes, int n_in,
                              void* d_out, int out_size, void* d_ws, size_t ws_size,
                              hipStream_t stream) {
  const float* node_repr = (const float*)d_in[0];
  const float* nbr_fea   = (const float*)d_in[1];
  const int*   nbr_idx   = (const int*)d_in[2];
  const float* fw1 = (const float*)d_in[3];
  const float* fb1 = (const float*)d_in[4];
  const float* fw2 = (const float*)d_in[5];
  const float* fb2 = (const float*)d_in[6];
  const float* uw1 = (const float*)d_in[7];
  const float* ub1 = (const float*)d_in[8];
  const float* uw2 = (const float*)d_in[9];
  const float* ub2 = (const float*)d_in[10];
  float* outp = (float*)d_out;
  short* u_ws = (short*)d_ws;   // bf16 u: NN*128*2B = 12.8 MB

  // k1: persistent, 3 blocks/CU target (LDS 54.2KB -> 3 fit in 160KB)
  k_filter_message<<<768, 256, 0, stream>>>(node_repr, nbr_fea, nbr_idx,
                                            fw1, fb1, fw2, fb2, outp);
  const int rowblocks = (NN + 31) / 32;        // 1563
  const int grid2 = (rowblocks + 3) / 4;       // 391
  k_update1<<<grid2, 256, 0, stream>>>(outp, uw1, ub1, u_ws);
  k_update2<<<grid2, 256, 0, stream>>>(u_ws, uw2, ub2, outp);
}

// Round 2
// 922.779 us; speedup vs baseline: 1.0367x; 1.0367x over previous
//
#include <hip/hip_runtime.h>

// InteractionBlock: N=50000 nodes, M=32 nbrs, HID=128, FILT=128, NBR=64
//  k1 : per-node fused filter MLP (bf16 MFMA) + filter-weighted neighbor sum -> message (d_out)
//  k2a: u = silu(msg@uw1+ub1) -> bf16 u in d_ws
//  k2b: out = u@uw2+ub2 -> d_out
//
// R1 -> R2 changes (latency-bound diagnosis: Occ 17.7%, VALU 14%, MFMA 5.5%, HBM 16%):
//  * nontemporal loads for nbr_fea / nbr_idx streams: stop flushing node_repr
//    out of L2/L3 (FETCH showed +820MB == gather volume missing cache)
//  * k1 block 256->512, 2 blocks/CU (LDS 108KB/CU), 16 waves/CU (~50% occ)
//
// MFMA layout conventions (gfx950, 16x16 family, verified m89/m91):
//   A/B frag (16x16x32): row/col = lane&15, k = (lane>>4)*8 + j  (short8)
//   A/B frag (16x16x16bf16_1k): same with 4 contiguous k (short4)
//   C/D: col = lane&15, row = (lane>>4)*4 + reg
// Trick: transposed GEMM1 (C=h^T) yields per-lane 4 consecutive filt values ==
// exactly the A-fragment of 16x16x16 for GEMM2 -> zero-shuffle handoff.

#define NN 50000
#define MM 32
#define HID 128
#define NBR 64

typedef __attribute__((ext_vector_type(4))) float f32x4;
typedef __attribute__((ext_vector_type(8))) short s16x8;
typedef __attribute__((ext_vector_type(4))) short s16x4;

__device__ __forceinline__ short f2bf(float x) {
  unsigned u = __builtin_bit_cast(unsigned, x);
  unsigned r = (u + 0x7FFFu + ((u >> 16) & 1u)) >> 16;
  return (short)r;
}

__device__ __forceinline__ float silu(float x) {
  return x / (1.0f + __expf(-x));
}

// ---------------------------------------------------------------- kernel 1
__global__ __launch_bounds__(512, 4) void k_filter_message(
    const float* __restrict__ node_repr, const float* __restrict__ nbr_fea,
    const int* __restrict__ nbr_idx, const float* __restrict__ fw1,
    const float* __restrict__ fb1, const float* __restrict__ fw2,
    const float* __restrict__ fb2, float* __restrict__ msg_out)
{
  // fw1T[f][k]: stride 72 shorts = 144B; fw2T[h][k]: stride 136 shorts = 272B
  __shared__ __align__(16) short s_w1[128 * 72];
  __shared__ __align__(16) short s_w2[128 * 136];
  __shared__ float s_b1[128];
  __shared__ float s_b2[128];

  const int tid = threadIdx.x;
  for (int i = tid; i < 64 * 128; i += 512) {      // fw1 given [k<64][f<128]
    int k = i >> 7, f = i & 127;
    s_w1[f * 72 + k] = f2bf(fw1[i]);
  }
  for (int i = tid; i < 128 * 128; i += 512) {     // fw2 given [k<128][h<128]
    int k = i >> 7, h = i & 127;
    s_w2[h * 136 + k] = f2bf(fw2[i]);
  }
  if (tid < 128) { s_b1[tid] = fb1[tid]; s_b2[tid] = fb2[tid]; }
  __syncthreads();

  const int wave = tid >> 6, lane = tid & 63;
  const int c = lane & 15, g = lane >> 4;
  const int gw = blockIdx.x * 8 + wave;
  const int stride = gridDim.x * 8;

  for (int n = gw; n < NN; n += stride) {
    const float* nf = nbr_fea + (size_t)n * (MM * NBR);

    // neighbor indices needed in epilogue: m = 16*mt + 4*g + r
    int idxm[8];
    #pragma unroll
    for (int mt = 0; mt < 2; ++mt)
      #pragma unroll
      for (int r = 0; r < 4; ++r)
        idxm[mt * 4 + r] = __builtin_nontemporal_load(
            nbr_idx + (size_t)n * MM + mt * 16 + g * 4 + r);

    // B1 frags: nbr^T, col m = 16mt+c, k = 32kt+8g..+7 (nontemporal stream)
    s16x8 b1[2][2];
    #pragma unroll
    for (int mt = 0; mt < 2; ++mt)
      #pragma unroll
      for (int kt = 0; kt < 2; ++kt) {
        const f32x4* src = reinterpret_cast<const f32x4*>(
            nf + (mt * 16 + c) * NBR + kt * 32 + g * 8);
        f32x4 lo = __builtin_nontemporal_load(src);
        f32x4 hi = __builtin_nontemporal_load(src + 1);
        s16x8 v;
        v[0] = f2bf(lo[0]); v[1] = f2bf(lo[1]); v[2] = f2bf(lo[2]); v[3] = f2bf(lo[3]);
        v[4] = f2bf(hi[0]); v[5] = f2bf(hi[1]); v[6] = f2bf(hi[2]); v[7] = f2bf(hi[3]);
        b1[mt][kt] = v;
      }

    // GEMM1 (transposed): h^T[filt][m] = fw1T . nbr^T   (16x16x32)
    f32x4 acc1[8][2];
    #pragma unroll
    for (int t = 0; t < 8; ++t)
      #pragma unroll
      for (int mt = 0; mt < 2; ++mt)
        acc1[t][mt] = f32x4{0.f, 0.f, 0.f, 0.f};
    #pragma unroll
    for (int kt = 0; kt < 2; ++kt)
      #pragma unroll
      for (int t = 0; t < 8; ++t) {
        s16x8 a1 = *reinterpret_cast<const s16x8*>(&s_w1[(t * 16 + c) * 72 + kt * 32 + g * 8]);
        #pragma unroll
        for (int mt = 0; mt < 2; ++mt)
          acc1[t][mt] = __builtin_amdgcn_mfma_f32_16x16x32_bf16(a1, b1[mt][kt], acc1[t][mt], 0, 0, 0);
      }

    // bias + silu + pack: P[kt][mt] = A-fragment of GEMM2 (zero shuffle)
    s16x4 P[8][2];
    #pragma unroll
    for (int t = 0; t < 8; ++t)
      #pragma unroll
      for (int mt = 0; mt < 2; ++mt) {
        s16x4 p;
        #pragma unroll
        for (int r = 0; r < 4; ++r) {
          float x = acc1[t][mt][r] + s_b1[t * 16 + g * 4 + r];
          p[r] = f2bf(silu(x));
        }
        P[t][mt] = p;
      }

    // GEMM2: filters[m][hid] = h~ . fw2   (16x16x16)
    f32x4 acc2[8][2];
    #pragma unroll
    for (int ct = 0; ct < 8; ++ct)
      #pragma unroll
      for (int mt = 0; mt < 2; ++mt)
        acc2[ct][mt] = f32x4{0.f, 0.f, 0.f, 0.f};
    #pragma unroll
    for (int ct = 0; ct < 8; ++ct)
      #pragma unroll
      for (int kt = 0; kt < 8; ++kt) {
        s16x4 b2 = *reinterpret_cast<const s16x4*>(&s_w2[(ct * 16 + c) * 136 + kt * 16 + g * 4]);
        #pragma unroll
        for (int mt = 0; mt < 2; ++mt)
          acc2[ct][mt] = __builtin_amdgcn_mfma_f32_16x16x16bf16_1k(P[kt][mt], b2, acc2[ct][mt], 0, 0, 0);
      }

    // epilogue: message[hid] = sum_m (filters[m][hid]+fb2[hid]) * node_repr[idx[m]][hid]
    #pragma unroll
    for (int ct = 0; ct < 8; ++ct) {
      const float bias = s_b2[ct * 16 + c];
      float s = 0.f;
      #pragma unroll
      for (int mt = 0; mt < 2; ++mt)
        #pragma unroll
        for (int r = 0; r < 4; ++r) {
          float fv = acc2[ct][mt][r] + bias;   // m = 16mt + 4g + r, hid = 16ct + c
          float nr = node_repr[(size_t)idxm[mt * 4 + r] * HID + ct * 16 + c];
          s += fv * nr;
        }
      s += __shfl_xor(s, 16, 64);
      s += __shfl_xor(s, 32, 64);
      if (g == 0) msg_out[(size_t)n * HID + ct * 16 + c] = s;
    }
  }
}

// ---------------------------------------------------------------- kernel 2a
// u^T = silu(uw1^T . msg^T + ub1) -> bf16 u[row][128] in ws
__global__ __launch_bounds__(256, 2) void k_update1(
    const float* __restrict__ msg, const float* __restrict__ uw1,
    const float* __restrict__ ub1, short* __restrict__ u_out)
{
  __shared__ __align__(16) short s_w1[128 * 136];   // uw1T[f][k], stride 136
  __shared__ float s_b1[128];
  const int tid = threadIdx.x;
  for (int i = tid; i < 128 * 128; i += 256) {      // uw1 given [k][f]
    int k = i >> 7, f = i & 127;
    s_w1[f * 136 + k] = f2bf(uw1[i]);
  }
  if (tid < 128) s_b1[tid] = ub1[tid];
  __syncthreads();

  const int wave = tid >> 6, lane = tid & 63;
  const int c = lane & 15, g = lane >> 4;
  const long base = (long)(blockIdx.x * 4 + wave) * 32;
  if (base >= NN) return;

  s16x8 bfr[2][4];
  #pragma unroll
  for (int mt = 0; mt < 2; ++mt)
    #pragma unroll
    for (int kt = 0; kt < 4; ++kt) {
      long row = base + mt * 16 + c; if (row > NN - 1) row = NN - 1;
      const float* src = msg + row * HID + kt * 32 + g * 8;
      float4 lo = *reinterpret_cast<const float4*>(src);
      float4 hi = *reinterpret_cast<const float4*>(src + 4);
      s16x8 v;
      v[0] = f2bf(lo.x); v[1] = f2bf(lo.y); v[2] = f2bf(lo.z); v[3] = f2bf(lo.w);
      v[4] = f2bf(hi.x); v[5] = f2bf(hi.y); v[6] = f2bf(hi.z); v[7] = f2bf(hi.w);
      bfr[mt][kt] = v;
    }

  f32x4 acc[8][2];
  #pragma unroll
  for (int t = 0; t < 8; ++t)
    #pragma unroll
    for (int mt = 0; mt < 2; ++mt)
      acc[t][mt] = f32x4{0.f, 0.f, 0.f, 0.f};
  #pragma unroll
  for (int kt = 0; kt < 4; ++kt)
    #pragma unroll
    for (int t = 0; t < 8; ++t) {
      s16x8 a = *reinterpret_cast<const s16x8*>(&s_w1[(t * 16 + c) * 136 + kt * 32 + g * 8]);
      #pragma unroll
      for (int mt = 0; mt < 2; ++mt)
        acc[t][mt] = __builtin_amdgcn_mfma_f32_16x16x32_bf16(a, bfr[mt][kt], acc[t][mt], 0, 0, 0);
    }

  #pragma unroll
  for (int t = 0; t < 8; ++t)
    #pragma unroll
    for (int mt = 0; mt < 2; ++mt) {
      long row = base + mt * 16 + c;
      if (row < NN) {
        s16x4 p;
        #pragma unroll
        for (int r = 0; r < 4; ++r) {
          float x = acc[t][mt][r] + s_b1[t * 16 + g * 4 + r];
          p[r] = f2bf(silu(x));
        }
        *reinterpret_cast<s16x4*>(&u_out[row * HID + t * 16 + g * 4]) = p;
      }
    }
}

// ---------------------------------------------------------------- kernel 2b
// out[m][hid] = u . uw2 + ub2   (16x16x16, A from bf16 u in ws)
__global__ __launch_bounds__(256, 2) void k_update2(
    const short* __restrict__ u, const float* __restrict__ uw2,
    const float* __restrict__ ub2, float* __restrict__ out)
{
  __shared__ __align__(16) short s_w2[128 * 136];   // uw2T[h][k]
  __shared__ float s_b2[128];
  const int tid = threadIdx.x;
  for (int i = tid; i < 128 * 128; i += 256) {      // uw2 given [k][h]
    int k = i >> 7, h = i & 127;
    s_w2[h * 136 + k] = f2bf(uw2[i]);
  }
  if (tid < 128) s_b2[tid] = ub2[tid];
  __syncthreads();

  const int wave = tid >> 6, lane = tid & 63;
  const int c = lane & 15, g = lane >> 4;
  const long base = (long)(blockIdx.x * 4 + wave) * 32;
  if (base >= NN) return;

  s16x4 afr[2][8];
  #pragma unroll
  for (int mt = 0; mt < 2; ++mt)
    #pragma unroll
    for (int kt = 0; kt < 8; ++kt) {
      long row = base + mt * 16 + c; if (row > NN - 1) row = NN - 1;
      afr[mt][kt] = *reinterpret_cast<const s16x4*>(&u[row * HID + kt * 16 + g * 4]);
    }

  f32x4 acc[8][2];
  #pragma unroll
  for (int ct = 0; ct < 8; ++ct)
    #pragma unroll
    for (int mt = 0; mt < 2; ++mt)
      acc[ct][mt] = f32x4{0.f, 0.f, 0.f, 0.f};
  #pragma unroll
  for (int ct = 0; ct < 8; ++ct)
    #pragma unroll
    for (int kt = 0; kt < 8; ++kt) {
      s16x4 b2 = *reinterpret_cast<const s16x4*>(&s_w2[(ct * 16 + c) * 136 + kt * 16 + g * 4]);
      #pragma unroll
      for (int mt = 0; mt < 2; ++mt)
        acc[ct][mt] = __builtin_amdgcn_mfma_f32_16x16x16bf16_1k(afr[mt][kt], b2, acc[ct][mt], 0, 0, 0);
    }

  #pragma unroll
  for (int ct = 0; ct < 8; ++ct) {
    const float bias = s_b2[ct * 16 + c];
    #pragma unroll
    for (int mt = 0; mt < 2; ++mt)
      #pragma unroll
      for (int r = 0; r < 4; ++r) {
        long row = base + mt * 16 + g * 4 + r;
        if (row < NN) out[row * HID + ct * 16 + c] = acc[ct][mt][r] + bias;
      }
  }
}

// ---------------------------------------------------------------- launch
extern "C" void kernel_launch(void* const* d_in, const int* in_sizes, int n_in,
                              void* d_out, int out_size, void* d_ws, size_t ws_size,
                              hipStream_t stream) {
  const float* node_repr = (const float*)d_in[0];
  const float* nbr_fea   = (const float*)d_in[1];
  const int*   nbr_idx   = (const int*)d_in[2];
  const float* fw1 = (const float*)d_in[3];
  const float* fb1 = (const float*)d_in[4];
  const float* fw2 = (const float*)d_in[5];
  const float* fb2 = (const float*)d_in[6];
  const float* uw1 = (const float*)d_in[7];
  const float* ub1 = (const float*)d_in[8];
  const float* uw2 = (const float*)d_in[9];
  const float* ub2 = (const float*)d_in[10];
  float* outp = (float*)d_out;
  short* u_ws = (short*)d_ws;   // bf16 u: NN*128*2B = 12.8 MB

  // k1: 512 blocks x 512 thr -> 2 blocks/CU (LDS 108KB/CU), 16 waves/CU
  k_filter_message<<<512, 512, 0, stream>>>(node_repr, nbr_fea, nbr_idx,
                                            fw1, fb1, fw2, fb2, outp);
  const int rowblocks = (NN + 31) / 32;        // 1563
  const int grid2 = (rowblocks + 3) / 4;       // 391
  k_update1<<<grid2, 256, 0, stream>>>(outp, uw1, ub1, u_ws);
  k_update2<<<grid2, 256, 0, stream>>>(u_ws, uw2, ub2, outp);
}

// Round 3
// 543.927 us; speedup vs baseline: 1.7587x; 1.6965x over previous
//
#include <hip/hip_runtime.h>

// InteractionBlock: N=50000 nodes, M=32 nbrs, HID=128, FILT=128, NBR=64
//  k1 : per-node fused filter MLP (bf16 MFMA) + filter-weighted neighbor sum -> message (d_out)
//  k2a: u = silu(msg@uw1+ub1) -> bf16 u in d_ws
//  k2b: out = u@uw2+ub2 -> d_out
//
// R2 -> R3 changes (diagnosis: VGPR=64 cap caused spills; gather was
// request-rate-bound: 256 scattered 64B-useful/128B-fetched transactions/node):
//  * __launch_bounds__(512,2): VGPR cap 256, no spills (R2's (512,4) capped at 64)
//  * gather restructured: filters (+fb2, f32) bounce through a PRIVATE per-wave
//    LDS tile; then all 64 lanes cooperatively read each gathered node_repr row
//    as ONE float2-coalesced 512B load (100% fetch utilization, 8x fewer
//    requests, 16 independent rows in flight). Two mt-halves keep LDS <= 122KB.
//
// MFMA layout conventions (gfx950, 16x16 family, verified m89/m91):
//   A/B frag (16x16x32): row/col = lane&15, k = (lane>>4)*8 + j  (short8)
//   A/B frag (16x16x16bf16_1k): same with 4 contiguous k (short4)
//   C/D: col = lane&15, row = (lane>>4)*4 + reg
// Trick: transposed GEMM1 (C=h^T) yields per-lane 4 consecutive filt values ==
// exactly the A-fragment of 16x16x16 for GEMM2 -> zero-shuffle handoff.

#define NN 50000
#define MM 32
#define HID 128
#define NBR 64

typedef __attribute__((ext_vector_type(4))) float f32x4;
typedef __attribute__((ext_vector_type(8))) short s16x8;
typedef __attribute__((ext_vector_type(4))) short s16x4;

__device__ __forceinline__ short f2bf(float x) {
  unsigned u = __builtin_bit_cast(unsigned, x);
  unsigned r = (u + 0x7FFFu + ((u >> 16) & 1u)) >> 16;
  return (short)r;
}

__device__ __forceinline__ float silu(float x) {
  return x / (1.0f + __expf(-x));
}

// ---------------------------------------------------------------- kernel 1
__global__ __launch_bounds__(512, 2) void k_filter_message(
    const float* __restrict__ node_repr, const float* __restrict__ nbr_fea,
    const int* __restrict__ nbr_idx, const float* __restrict__ fw1,
    const float* __restrict__ fb1, const float* __restrict__ fw2,
    const float* __restrict__ fb2, float* __restrict__ msg_out)
{
  // fw1T[f][k]: stride 72 shorts; fw2T[h][k]: stride 136 shorts
  __shared__ __align__(16) short s_w1[128 * 72];      // 18.4 KB
  __shared__ __align__(16) short s_w2[128 * 136];     // 34.8 KB
  __shared__ float s_b1[128];
  __shared__ float s_b2[128];
  __shared__ __align__(16) float s_filt[8 * 16 * 132]; // per-wave [16][132] f32, 67.6 KB

  const int tid = threadIdx.x;
  for (int i = tid; i < 64 * 128; i += 512) {      // fw1 given [k<64][f<128]
    int k = i >> 7, f = i & 127;
    s_w1[f * 72 + k] = f2bf(fw1[i]);
  }
  for (int i = tid; i < 128 * 128; i += 512) {     // fw2 given [k<128][h<128]
    int k = i >> 7, h = i & 127;
    s_w2[h * 136 + k] = f2bf(fw2[i]);
  }
  if (tid < 128) { s_b1[tid] = fb1[tid]; s_b2[tid] = fb2[tid]; }
  __syncthreads();

  const int wave = tid >> 6, lane = tid & 63;
  const int c = lane & 15, g = lane >> 4;
  float* __restrict__ ft = s_filt + wave * (16 * 132);   // private per-wave tile
  const int gw = blockIdx.x * 8 + wave;
  const int stride = gridDim.x * 8;

  for (int n = gw; n < NN; n += stride) {
    const float* nf = nbr_fea + (size_t)n * (MM * NBR);

    // B1 frags: nbr^T, col m = 16mt+c, k = 32kt+8g..+7 (nontemporal stream)
    s16x8 b1[2][2];
    #pragma unroll
    for (int mt = 0; mt < 2; ++mt)
      #pragma unroll
      for (int kt = 0; kt < 2; ++kt) {
        const f32x4* src = reinterpret_cast<const f32x4*>(
            nf + (mt * 16 + c) * NBR + kt * 32 + g * 8);
        f32x4 lo = __builtin_nontemporal_load(src);
        f32x4 hi = __builtin_nontemporal_load(src + 1);
        s16x8 v;
        v[0] = f2bf(lo[0]); v[1] = f2bf(lo[1]); v[2] = f2bf(lo[2]); v[3] = f2bf(lo[3]);
        v[4] = f2bf(hi[0]); v[5] = f2bf(hi[1]); v[6] = f2bf(hi[2]); v[7] = f2bf(hi[3]);
        b1[mt][kt] = v;
      }

    // GEMM1 (transposed): h^T[filt][m] = fw1T . nbr^T   (16x16x32)
    f32x4 acc1[8][2];
    #pragma unroll
    for (int t = 0; t < 8; ++t)
      #pragma unroll
      for (int mt = 0; mt < 2; ++mt)
        acc1[t][mt] = f32x4{0.f, 0.f, 0.f, 0.f};
    #pragma unroll
    for (int kt = 0; kt < 2; ++kt)
      #pragma unroll
      for (int t = 0; t < 8; ++t) {
        s16x8 a1 = *reinterpret_cast<const s16x8*>(&s_w1[(t * 16 + c) * 72 + kt * 32 + g * 8]);
        #pragma unroll
        for (int mt = 0; mt < 2; ++mt)
          acc1[t][mt] = __builtin_amdgcn_mfma_f32_16x16x32_bf16(a1, b1[mt][kt], acc1[t][mt], 0, 0, 0);
      }

    // bias + silu + pack: P[kt][mt] = A-fragment of GEMM2 (zero shuffle)
    s16x4 P[8][2];
    #pragma unroll
    for (int t = 0; t < 8; ++t)
      #pragma unroll
      for (int mt = 0; mt < 2; ++mt) {
        s16x4 p;
        #pragma unroll
        for (int r = 0; r < 4; ++r) {
          float x = acc1[t][mt][r] + s_b1[t * 16 + g * 4 + r];
          p[r] = f2bf(silu(x));
        }
        P[t][mt] = p;
      }

    // GEMM2: filters[m][hid] = h~ . fw2   (16x16x16)
    f32x4 acc2[8][2];
    #pragma unroll
    for (int ct = 0; ct < 8; ++ct)
      #pragma unroll
      for (int mt = 0; mt < 2; ++mt)
        acc2[ct][mt] = f32x4{0.f, 0.f, 0.f, 0.f};
    #pragma unroll
    for (int ct = 0; ct < 8; ++ct)
      #pragma unroll
      for (int kt = 0; kt < 8; ++kt) {
        s16x4 b2 = *reinterpret_cast<const s16x4*>(&s_w2[(ct * 16 + c) * 136 + kt * 16 + g * 4]);
        #pragma unroll
        for (int mt = 0; mt < 2; ++mt)
          acc2[ct][mt] = __builtin_amdgcn_mfma_f32_16x16x16bf16_1k(P[kt][mt], b2, acc2[ct][mt], 0, 0, 0);
      }

    // epilogue: message[hid] = sum_m (filters[m][hid]+fb2[hid]) * node_repr[idx[m]][hid]
    // per-wave LDS bounce (f32 filters), then wave-coalesced 512B row gathers.
    float msg0 = 0.f, msg1 = 0.f;      // hid = 2*lane, 2*lane+1
    #pragma unroll
    for (int mt = 0; mt < 2; ++mt) {
      // write filters for m = 16mt + (4g+r), hid = 16ct + c   (2-way banks, free)
      #pragma unroll
      for (int ct = 0; ct < 8; ++ct) {
        const float bias = s_b2[ct * 16 + c];
        #pragma unroll
        for (int r = 0; r < 4; ++r)
          ft[(4 * g + r) * 132 + ct * 16 + c] = acc2[ct][mt][r] + bias;
      }
      // wave-private tile: same-wave DS ordering; compiler inserts lgkmcnt
      #pragma unroll
      for (int m = 0; m < 16; ++m) {
        const int idx = nbr_idx[(size_t)n * MM + mt * 16 + m];   // uniform bcast
        const float2 nr = *reinterpret_cast<const float2*>(
            node_repr + (size_t)idx * HID + 2 * lane);           // 512B/row, 1 instr
        const float2 fv = *reinterpret_cast<const float2*>(&ft[m * 132 + 2 * lane]);
        msg0 += fv.x * nr.x;
        msg1 += fv.y * nr.y;
      }
    }
    *reinterpret_cast<float2*>(msg_out + (size_t)n * HID + 2 * lane) =
        float2{msg0, msg1};
  }
}

// ---------------------------------------------------------------- kernel 2a
// u^T = silu(uw1^T . msg^T + ub1) -> bf16 u[row][128] in ws
__global__ __launch_bounds__(256, 2) void k_update1(
    const float* __restrict__ msg, const float* __restrict__ uw1,
    const float* __restrict__ ub1, short* __restrict__ u_out)
{
  __shared__ __align__(16) short s_w1[128 * 136];   // uw1T[f][k], stride 136
  __shared__ float s_b1[128];
  const int tid = threadIdx.x;
  for (int i = tid; i < 128 * 128; i += 256) {      // uw1 given [k][f]
    int k = i >> 7, f = i & 127;
    s_w1[f * 136 + k] = f2bf(uw1[i]);
  }
  if (tid < 128) s_b1[tid] = ub1[tid];
  __syncthreads();

  const int wave = tid >> 6, lane = tid & 63;
  const int c = lane & 15, g = lane >> 4;
  const long base = (long)(blockIdx.x * 4 + wave) * 32;
  if (base >= NN) return;

  s16x8 bfr[2][4];
  #pragma unroll
  for (int mt = 0; mt < 2; ++mt)
    #pragma unroll
    for (int kt = 0; kt < 4; ++kt) {
      long row = base + mt * 16 + c; if (row > NN - 1) row = NN - 1;
      const float* src = msg + row * HID + kt * 32 + g * 8;
      float4 lo = *reinterpret_cast<const float4*>(src);
      float4 hi = *reinterpret_cast<const float4*>(src + 4);
      s16x8 v;
      v[0] = f2bf(lo.x); v[1] = f2bf(lo.y); v[2] = f2bf(lo.z); v[3] = f2bf(lo.w);
      v[4] = f2bf(hi.x); v[5] = f2bf(hi.y); v[6] = f2bf(hi.z); v[7] = f2bf(hi.w);
      bfr[mt][kt] = v;
    }

  f32x4 acc[8][2];
  #pragma unroll
  for (int t = 0; t < 8; ++t)
    #pragma unroll
    for (int mt = 0; mt < 2; ++mt)
      acc[t][mt] = f32x4{0.f, 0.f, 0.f, 0.f};
  #pragma unroll
  for (int kt = 0; kt < 4; ++kt)
    #pragma unroll
    for (int t = 0; t < 8; ++t) {
      s16x8 a = *reinterpret_cast<const s16x8*>(&s_w1[(t * 16 + c) * 136 + kt * 32 + g * 8]);
      #pragma unroll
      for (int mt = 0; mt < 2; ++mt)
        acc[t][mt] = __builtin_amdgcn_mfma_f32_16x16x32_bf16(a, bfr[mt][kt], acc[t][mt], 0, 0, 0);
    }

  #pragma unroll
  for (int t = 0; t < 8; ++t)
    #pragma unroll
    for (int mt = 0; mt < 2; ++mt) {
      long row = base + mt * 16 + c;
      if (row < NN) {
        s16x4 p;
        #pragma unroll
        for (int r = 0; r < 4; ++r) {
          float x = acc[t][mt][r] + s_b1[t * 16 + g * 4 + r];
          p[r] = f2bf(silu(x));
        }
        *reinterpret_cast<s16x4*>(&u_out[row * HID + t * 16 + g * 4]) = p;
      }
    }
}

// ---------------------------------------------------------------- kernel 2b
// out[m][hid] = u . uw2 + ub2   (16x16x16, A from bf16 u in ws)
__global__ __launch_bounds__(256, 2) void k_update2(
    const short* __restrict__ u, const float* __restrict__ uw2,
    const float* __restrict__ ub2, float* __restrict__ out)
{
  __shared__ __align__(16) short s_w2[128 * 136];   // uw2T[h][k]
  __shared__ float s_b2[128];
  const int tid = threadIdx.x;
  for (int i = tid; i < 128 * 128; i += 256) {      // uw2 given [k][h]
    int k = i >> 7, h = i & 127;
    s_w2[h * 136 + k] = f2bf(uw2[i]);
  }
  if (tid < 128) s_b2[tid] = ub2[tid];
  __syncthreads();

  const int wave = tid >> 6, lane = tid & 63;
  const int c = lane & 15, g = lane >> 4;
  const long base = (long)(blockIdx.x * 4 + wave) * 32;
  if (base >= NN) return;

  s16x4 afr[2][8];
  #pragma unroll
  for (int mt = 0; mt < 2; ++mt)
    #pragma unroll
    for (int kt = 0; kt < 8; ++kt) {
      long row = base + mt * 16 + c; if (row > NN - 1) row = NN - 1;
      afr[mt][kt] = *reinterpret_cast<const s16x4*>(&u[row * HID + kt * 16 + g * 4]);
    }

  f32x4 acc[8][2];
  #pragma unroll
  for (int ct = 0; ct < 8; ++ct)
    #pragma unroll
    for (int mt = 0; mt < 2; ++mt)
      acc[ct][mt] = f32x4{0.f, 0.f, 0.f, 0.f};
  #pragma unroll
  for (int ct = 0; ct < 8; ++ct)
    #pragma unroll
    for (int kt = 0; kt < 8; ++kt) {
      s16x4 b2 = *reinterpret_cast<const s16x4*>(&s_w2[(ct * 16 + c) * 136 + kt * 16 + g * 4]);
      #pragma unroll
      for (int mt = 0; mt < 2; ++mt)
        acc[ct][mt] = __builtin_amdgcn_mfma_f32_16x16x16bf16_1k(afr[mt][kt], b2, acc[ct][mt], 0, 0, 0);
    }

  #pragma unroll
  for (int ct = 0; ct < 8; ++ct) {
    const float bias = s_b2[ct * 16 + c];
    #pragma unroll
    for (int mt = 0; mt < 2; ++mt)
      #pragma unroll
      for (int r = 0; r < 4; ++r) {
        long row = base + mt * 16 + g * 4 + r;
        if (row < NN) out[row * HID + ct * 16 + c] = acc[ct][mt][r] + bias;
      }
  }
}

// ---------------------------------------------------------------- launch
extern "C" void kernel_launch(void* const* d_in, const int* in_sizes, int n_in,
                              void* d_out, int out_size, void* d_ws, size_t ws_size,
                              hipStream_t stream) {
  const float* node_repr = (const float*)d_in[0];
  const float* nbr_fea   = (const float*)d_in[1];
  const int*   nbr_idx   = (const int*)d_in[2];
  const float* fw1 = (const float*)d_in[3];
  const float* fb1 = (const float*)d_in[4];
  const float* fw2 = (const float*)d_in[5];
  const float* fb2 = (const float*)d_in[6];
  const float* uw1 = (const float*)d_in[7];
  const float* ub1 = (const float*)d_in[8];
  const float* uw2 = (const float*)d_in[9];
  const float* ub2 = (const float*)d_in[10];
  float* outp = (float*)d_out;
  short* u_ws = (short*)d_ws;   // bf16 u: NN*128*2B = 12.8 MB

  // k1: 256 blocks x 512 thr, 1 block/CU (LDS 122KB), 8 waves/CU, VGPR cap 256
  k_filter_message<<<256, 512, 0, stream>>>(node_repr, nbr_fea, nbr_idx,
                                            fw1, fb1, fw2, fb2, outp);
  const int rowblocks = (NN + 31) / 32;        // 1563
  const int grid2 = (rowblocks + 3) / 4;       // 391
  k_update1<<<grid2, 256, 0, stream>>>(outp, uw1, ub1, u_ws);
  k_update2<<<grid2, 256, 0, stream>>>(u_ws, uw2, ub2, outp);
}

// Round 4
// 525.687 us; speedup vs baseline: 1.8197x; 1.0347x over previous
//
#include <hip/hip_runtime.h>

// InteractionBlock: N=50000 nodes, M=32 nbrs, HID=128, FILT=128, NBR=64
//  k1 : per-node fused filter MLP (bf16 MFMA) + filter-weighted neighbor sum -> message (d_out)
//  k2a: u = silu(msg@uw1+ub1) -> bf16 u in d_ws
//  k2b: out = u@uw2+ub2 -> d_out
//
// R3 -> R4 changes (diagnosis: 1 block/CU (LDS 122KB) capped occupancy at 22.5%;
// LDS filter-tile bounce was only a layout transpose):
//  * GEMM2 computed TRANSPOSED (swap mfma args: A=w2 frag, B=P frag — identical
//    register operands, A/B frag lane-maps are the same). C-layout then gives
//    each lane filter[m=c][hid=16ct+4g+{0..3}] -> gather is an in-lane float4
//    load; s_filt LDS tile (67.6KB) and all tile DS-ops eliminated.
//  * m-sum = sum over 16 c-lanes via 4 DPP rounds (quad_perm xor1/xor2,
//    row_ror:4/8) — pure VALU, no LDS pipe.
//  * LDS 54.2KB -> 2 blocks/CU, 16 waves/CU; GEMM1 restructured per-t so peak
//    VGPR fits the 128 cap (4 waves/SIMD) without spills.
//
// MFMA layout conventions (gfx950, 16x16 family, verified m89/m91):
//   A frag (16x16x32): row = lane&15, k = (lane>>4)*8 + j  (short8)
//   A/B frag (16x16x16bf16_1k): row/col = lane&15, k = (lane>>4)*4 + j (short4)
//   C/D: col = lane&15, row = (lane>>4)*4 + reg

#define NN 50000
#define MM 32
#define HID 128
#define NBR 64

typedef __attribute__((ext_vector_type(4))) float f32x4;
typedef __attribute__((ext_vector_type(8))) short s16x8;
typedef __attribute__((ext_vector_type(4))) short s16x4;

__device__ __forceinline__ short f2bf(float x) {
  unsigned u = __builtin_bit_cast(unsigned, x);
  unsigned r = (u + 0x7FFFu + ((u >> 16) & 1u)) >> 16;
  return (short)r;
}

__device__ __forceinline__ float silu(float x) {
  return x / (1.0f + __expf(-x));
}

// sum over the 16 lanes of a row-group (lane&15 varies): rotate-reduce, all VALU
__device__ __forceinline__ float rowsum16(float x) {
  int v = __builtin_bit_cast(int, x);
  v = __builtin_bit_cast(int,
      __builtin_bit_cast(float, v) +
      __builtin_bit_cast(float, __builtin_amdgcn_update_dpp(0, v, 0xB1, 0xF, 0xF, false)));  // xor1
  v = __builtin_bit_cast(int,
      __builtin_bit_cast(float, v) +
      __builtin_bit_cast(float, __builtin_amdgcn_update_dpp(0, v, 0x4E, 0xF, 0xF, false)));  // xor2
  v = __builtin_bit_cast(int,
      __builtin_bit_cast(float, v) +
      __builtin_bit_cast(float, __builtin_amdgcn_update_dpp(0, v, 0x124, 0xF, 0xF, false))); // ror4
  v = __builtin_bit_cast(int,
      __builtin_bit_cast(float, v) +
      __builtin_bit_cast(float, __builtin_amdgcn_update_dpp(0, v, 0x128, 0xF, 0xF, false))); // ror8
  return __builtin_bit_cast(float, v);
}

// ---------------------------------------------------------------- kernel 1
__global__ __launch_bounds__(512, 2) void k_filter_message(
    const float* __restrict__ node_repr, const float* __restrict__ nbr_fea,
    const int* __restrict__ nbr_idx, const float* __restrict__ fw1,
    const float* __restrict__ fb1, const float* __restrict__ fw2,
    const float* __restrict__ fb2, float* __restrict__ msg_out)
{
  // fw1T[f][k]: stride 72 shorts; fw2T[h][k]: stride 136 shorts
  __shared__ __align__(16) short s_w1[128 * 72];      // 18.4 KB
  __shared__ __align__(16) short s_w2[128 * 136];     // 34.8 KB
  __shared__ float s_b1[128];
  __shared__ __align__(16) float s_b2[128];           // read as f32x4

  const int tid = threadIdx.x;
  for (int i = tid; i < 64 * 128; i += 512) {      // fw1 given [k<64][f<128]
    int k = i >> 7, f = i & 127;
    s_w1[f * 72 + k] = f2bf(fw1[i]);
  }
  for (int i = tid; i < 128 * 128; i += 512) {     // fw2 given [k<128][h<128]
    int k = i >> 7, h = i & 127;
    s_w2[h * 136 + k] = f2bf(fw2[i]);
  }
  if (tid < 128) { s_b1[tid] = fb1[tid]; s_b2[tid] = fb2[tid]; }
  __syncthreads();

  const int wave = tid >> 6, lane = tid & 63;
  const int c = lane & 15, g = lane >> 4;
  const int gw = blockIdx.x * 8 + wave;
  const int stride = gridDim.x * 8;

  for (int n = gw; n < NN; n += stride) {
    const float* nf = nbr_fea + (size_t)n * (MM * NBR);

    // per-lane neighbor index for the gather: m = 16*mt + c
    int idx0 = nbr_idx[(size_t)n * MM + c];
    int idx1 = nbr_idx[(size_t)n * MM + 16 + c];

    // B1 frags: nbr^T, col m = 16mt+c, k = 32kt+8g..+7 (nontemporal stream)
    s16x8 b1[2][2];
    #pragma unroll
    for (int mt = 0; mt < 2; ++mt)
      #pragma unroll
      for (int kt = 0; kt < 2; ++kt) {
        const f32x4* src = reinterpret_cast<const f32x4*>(
            nf + (mt * 16 + c) * NBR + kt * 32 + g * 8);
        f32x4 lo = __builtin_nontemporal_load(src);
        f32x4 hi = __builtin_nontemporal_load(src + 1);
        s16x8 v;
        v[0] = f2bf(lo[0]); v[1] = f2bf(lo[1]); v[2] = f2bf(lo[2]); v[3] = f2bf(lo[3]);
        v[4] = f2bf(hi[0]); v[5] = f2bf(hi[1]); v[6] = f2bf(hi[2]); v[7] = f2bf(hi[3]);
        b1[mt][kt] = v;
      }

    // GEMM1 (transposed): h^T[filt][m] = fw1T . nbr^T  (16x16x32), per-t accs
    // then bias+silu+pack: P[t][mt] holds h~[m=16mt+c][f=16t+4g+{0..3}]
    s16x4 P[8][2];
    #pragma unroll
    for (int t = 0; t < 8; ++t) {
      f32x4 a0 = f32x4{0.f, 0.f, 0.f, 0.f};
      f32x4 a1 = f32x4{0.f, 0.f, 0.f, 0.f};
      #pragma unroll
      for (int kt = 0; kt < 2; ++kt) {
        s16x8 w1f = *reinterpret_cast<const s16x8*>(&s_w1[(t * 16 + c) * 72 + kt * 32 + g * 8]);
        a0 = __builtin_amdgcn_mfma_f32_16x16x32_bf16(w1f, b1[0][kt], a0, 0, 0, 0);
        a1 = __builtin_amdgcn_mfma_f32_16x16x32_bf16(w1f, b1[1][kt], a1, 0, 0, 0);
      }
      s16x4 p0, p1;
      #pragma unroll
      for (int r = 0; r < 4; ++r) {
        float bias = s_b1[t * 16 + g * 4 + r];
        p0[r] = f2bf(silu(a0[r] + bias));
        p1[r] = f2bf(silu(a1[r] + bias));
      }
      P[t][0] = p0;
      P[t][1] = p1;
    }

    // GEMM2 TRANSPOSED + fused gather:
    //   filtersT = fw2T . h~T : acc2T[ct] lane-holds filter[m=16mt+c][hid=16ct+4g+r]
    //   pacc[ct] += (filter + fb2) * node_repr[idx_m][hid]   (in-lane float4)
    f32x4 pacc[8];
    #pragma unroll
    for (int ct = 0; ct < 8; ++ct) pacc[ct] = f32x4{0.f, 0.f, 0.f, 0.f};

    #pragma unroll
    for (int mt = 0; mt < 2; ++mt) {
      const float* nrp = node_repr + (size_t)(mt ? idx1 : idx0) * HID;
      #pragma unroll
      for (int ct = 0; ct < 8; ++ct) {
        f32x4 acc2t = f32x4{0.f, 0.f, 0.f, 0.f};
        #pragma unroll
        for (int kt = 0; kt < 8; ++kt) {
          s16x4 w2f = *reinterpret_cast<const s16x4*>(&s_w2[(ct * 16 + c) * 136 + kt * 16 + g * 4]);
          // swapped args: A = w2 frag, B = P  ->  C = filtersT
          acc2t = __builtin_amdgcn_mfma_f32_16x16x16bf16_1k(w2f, P[kt][mt], acc2t, 0, 0, 0);
        }
        f32x4 nr = *reinterpret_cast<const f32x4*>(nrp + ct * 16 + 4 * g);
        f32x4 fb = *reinterpret_cast<const f32x4*>(&s_b2[ct * 16 + 4 * g]);
        #pragma unroll
        for (int r = 0; r < 4; ++r)
          pacc[ct][r] += (acc2t[r] + fb[r]) * nr[r];
      }
    }

    // m-sum: reduce over the 16 c-lanes (DPP, result replicated); c==0 stores
    #pragma unroll
    for (int ct = 0; ct < 8; ++ct) {
      f32x4 s;
      #pragma unroll
      for (int r = 0; r < 4; ++r) s[r] = rowsum16(pacc[ct][r]);
      if (c == 0)
        *reinterpret_cast<f32x4*>(msg_out + (size_t)n * HID + ct * 16 + 4 * g) = s;
    }
  }
}

// ---------------------------------------------------------------- kernel 2a
// u^T = silu(uw1^T . msg^T + ub1) -> bf16 u[row][128] in ws
__global__ __launch_bounds__(256, 2) void k_update1(
    const float* __restrict__ msg, const float* __restrict__ uw1,
    const float* __restrict__ ub1, short* __restrict__ u_out)
{
  __shared__ __align__(16) short s_w1[128 * 136];   // uw1T[f][k], stride 136
  __shared__ float s_b1[128];
  const int tid = threadIdx.x;
  for (int i = tid; i < 128 * 128; i += 256) {      // uw1 given [k][f]
    int k = i >> 7, f = i & 127;
    s_w1[f * 136 + k] = f2bf(uw1[i]);
  }
  if (tid < 128) s_b1[tid] = ub1[tid];
  __syncthreads();

  const int wave = tid >> 6, lane = tid & 63;
  const int c = lane & 15, g = lane >> 4;
  const long base = (long)(blockIdx.x * 4 + wave) * 32;
  if (base >= NN) return;

  s16x8 bfr[2][4];
  #pragma unroll
  for (int mt = 0; mt < 2; ++mt)
    #pragma unroll
    for (int kt = 0; kt < 4; ++kt) {
      long row = base + mt * 16 + c; if (row > NN - 1) row = NN - 1;
      const float* src = msg + row * HID + kt * 32 + g * 8;
      float4 lo = *reinterpret_cast<const float4*>(src);
      float4 hi = *reinterpret_cast<const float4*>(src + 4);
      s16x8 v;
      v[0] = f2bf(lo.x); v[1] = f2bf(lo.y); v[2] = f2bf(lo.z); v[3] = f2bf(lo.w);
      v[4] = f2bf(hi.x); v[5] = f2bf(hi.y); v[6] = f2bf(hi.z); v[7] = f2bf(hi.w);
      bfr[mt][kt] = v;
    }

  f32x4 acc[8][2];
  #pragma unroll
  for (int t = 0; t < 8; ++t)
    #pragma unroll
    for (int mt = 0; mt < 2; ++mt)
      acc[t][mt] = f32x4{0.f, 0.f, 0.f, 0.f};
  #pragma unroll
  for (int kt = 0; kt < 4; ++kt)
    #pragma unroll
    for (int t = 0; t < 8; ++t) {
      s16x8 a = *reinterpret_cast<const s16x8*>(&s_w1[(t * 16 + c) * 136 + kt * 32 + g * 8]);
      #pragma unroll
      for (int mt = 0; mt < 2; ++mt)
        acc[t][mt] = __builtin_amdgcn_mfma_f32_16x16x32_bf16(a, bfr[mt][kt], acc[t][mt], 0, 0, 0);
    }

  #pragma unroll
  for (int t = 0; t < 8; ++t)
    #pragma unroll
    for (int mt = 0; mt < 2; ++mt) {
      long row = base + mt * 16 + c;
      if (row < NN) {
        s16x4 p;
        #pragma unroll
        for (int r = 0; r < 4; ++r) {
          float x = acc[t][mt][r] + s_b1[t * 16 + g * 4 + r];
          p[r] = f2bf(silu(x));
        }
        *reinterpret_cast<s16x4*>(&u_out[row * HID + t * 16 + g * 4]) = p;
      }
    }
}

// ---------------------------------------------------------------- kernel 2b
// out[m][hid] = u . uw2 + ub2   (16x16x16, A from bf16 u in ws)
__global__ __launch_bounds__(256, 2) void k_update2(
    const short* __restrict__ u, const float* __restrict__ uw2,
    const float* __restrict__ ub2, float* __restrict__ out)
{
  __shared__ __align__(16) short s_w2[128 * 136];   // uw2T[h][k]
  __shared__ float s_b2[128];
  const int tid = threadIdx.x;
  for (int i = tid; i < 128 * 128; i += 256) {      // uw2 given [k][h]
    int k = i >> 7, h = i & 127;
    s_w2[h * 136 + k] = f2bf(uw2[i]);
  }
  if (tid < 128) s_b2[tid] = ub2[tid];
  __syncthreads();

  const int wave = tid >> 6, lane = tid & 63;
  const int c = lane & 15, g = lane >> 4;
  const long base = (long)(blockIdx.x * 4 + wave) * 32;
  if (base >= NN) return;

  s16x4 afr[2][8];
  #pragma unroll
  for (int mt = 0; mt < 2; ++mt)
    #pragma unroll
    for (int kt = 0; kt < 8; ++kt) {
      long row = base + mt * 16 + c; if (row > NN - 1) row = NN - 1;
      afr[mt][kt] = *reinterpret_cast<const s16x4*>(&u[row * HID + kt * 16 + g * 4]);
    }

  f32x4 acc[8][2];
  #pragma unroll
  for (int ct = 0; ct < 8; ++ct)
    #pragma unroll
    for (int mt = 0; mt < 2; ++mt)
      acc[ct][mt] = f32x4{0.f, 0.f, 0.f, 0.f};
  #pragma unroll
  for (int ct = 0; ct < 8; ++ct)
    #pragma unroll
    for (int kt = 0; kt < 8; ++kt) {
      s16x4 b2 = *reinterpret_cast<const s16x4*>(&s_w2[(ct * 16 + c) * 136 + kt * 16 + g * 4]);
      #pragma unroll
      for (int mt = 0; mt < 2; ++mt)
        acc[ct][mt] = __builtin_amdgcn_mfma_f32_16x16x16bf16_1k(afr[mt][kt], b2, acc[ct][mt], 0, 0, 0);
    }

  #pragma unroll
  for (int ct = 0; ct < 8; ++ct) {
    const float bias = s_b2[ct * 16 + c];
    #pragma unroll
    for (int mt = 0; mt < 2; ++mt)
      #pragma unroll
      for (int r = 0; r < 4; ++r) {
        long row = base + mt * 16 + g * 4 + r;
        if (row < NN) out[row * HID + ct * 16 + c] = acc[ct][mt][r] + bias;
      }
  }
}

// ---------------------------------------------------------------- launch
extern "C" void kernel_launch(void* const* d_in, const int* in_sizes, int n_in,
                              void* d_out, int out_size, void* d_ws, size_t ws_size,
                              hipStream_t stream) {
  const float* node_repr = (const float*)d_in[0];
  const float* nbr_fea   = (const float*)d_in[1];
  const int*   nbr_idx   = (const int*)d_in[2];
  const float* fw1 = (const float*)d_in[3];
  const float* fb1 = (const float*)d_in[4];
  const float* fw2 = (const float*)d_in[5];
  const float* fb2 = (const float*)d_in[6];
  const float* uw1 = (const float*)d_in[7];
  const float* ub1 = (const float*)d_in[8];
  const float* uw2 = (const float*)d_in[9];
  const float* ub2 = (const float*)d_in[10];
  float* outp = (float*)d_out;
  short* u_ws = (short*)d_ws;   // bf16 u: NN*128*2B = 12.8 MB

  // k1: 512 blocks x 512 thr, 2 blocks/CU (LDS 54.2KB), 16 waves/CU, VGPR<=128
  k_filter_message<<<512, 512, 0, stream>>>(node_repr, nbr_fea, nbr_idx,
                                            fw1, fb1, fw2, fb2, outp);
  const int rowblocks = (NN + 31) / 32;        // 1563
  const int grid2 = (rowblocks + 3) / 4;       // 391
  k_update1<<<grid2, 256, 0, stream>>>(outp, uw1, ub1, u_ws);
  k_update2<<<grid2, 256, 0, stream>>>(u_ws, uw2, ub2, outp);
}